// Round 1
// baseline (438.286 us; speedup 1.0000x reference)
//
#include <hip/hip_runtime.h>

// EnsembleFC: out = relu(relu(x@W1+b1)@W2+b2)@W3+b3, E=16, B=8192, D=H=512, DOUT=1
// Strategy: bf16 hi/lo split (3-MFMA emulated fp32) fully-fused MLP.
//  - prep kernels split x/W1/W2 into hi/lo bf16 packed in MFMA fragment order
//  - fused kernel: block = (e, 64-row batch tile); h1 in LDS (XOR-swizzled),
//    h2 stays in accumulators, W streamed global->VGPR (L2-resident per XCD).

#define E_N   16
#define DIN   512
#define HID   512
#define BATCH 8192
#define BT    64
#define NBT   (BATCH / BT)   // 128
#define NBLK  (E_N * NBT)    // 2048

typedef __attribute__((ext_vector_type(8))) short bf16x8;
typedef __attribute__((ext_vector_type(4))) float f32x4;

#define IMG_BYTES   131072                      // per-btile x/h image: [2 s][64 r][1024 B], swizzled
#define XPACK_BYTES ((size_t)NBT * IMG_BYTES)   // 16.78 MB
#define WP_PER_E    (32 * 16 * 2048)            // [32 nt][16 kb][2 s][64 lane][16 B] = 1 MB
#define WP_BYTES    ((size_t)E_N * WP_PER_E)    // 16.78 MB

__device__ __forceinline__ short f2bf(float f) {
  unsigned u = __builtin_bit_cast(unsigned, f);
  u += 0x7fffu + ((u >> 16) & 1u);              // RTNE
  return (short)(u >> 16);
}
__device__ __forceinline__ float bf2f(short s) {
  unsigned u = ((unsigned)(unsigned short)s) << 16;
  return __builtin_bit_cast(float, u);
}

// ---- prep: split x into hi/lo bf16 images, swizzle baked in ----
__global__ void pack_x_kernel(const float* __restrict__ x, char* __restrict__ xp) {
  int t  = blockIdx.x * blockDim.x + threadIdx.x;  // 524288 threads
  int b  = t >> 6;
  int c8 = (t & 63) << 3;
  const float* src = x + (size_t)b * DIN + c8;
  bf16x8 hi, lo;
#pragma unroll
  for (int j = 0; j < 8; ++j) {
    float v = src[j];
    short h = f2bf(v);
    hi[j] = h;
    lo[j] = f2bf(v - bf2f(h));
  }
  int btile = b >> 6, r = b & 63;
  char* img = xp + (size_t)btile * IMG_BYTES;
  int inrow = (c8 << 1) ^ ((r & 7) << 4);       // XOR swizzle (G4)
  *(bf16x8*)(img + (r << 10) + inrow) = hi;
  *(bf16x8*)(img + 65536 + (r << 10) + inrow) = lo;
}

// ---- prep: split W into hi/lo bf16 B-fragments (16x16x32 layout) ----
// frag element: W[e][kb*32 + (lane>>4)*8 + j][nt*16 + (lane&15)]
__global__ void pack_w_kernel(const float* __restrict__ w, char* __restrict__ wp) {
  int t    = blockIdx.x * blockDim.x + threadIdx.x;  // 524288 threads
  int lane = t & 63;
  int kb   = (t >> 6) & 15;
  int nt   = (t >> 10) & 31;
  int e    = t >> 15;
  int k0 = kb * 32 + (lane >> 4) * 8;
  int n  = nt * 16 + (lane & 15);
  const float* src = w + ((size_t)e * DIN + k0) * HID + n;
  bf16x8 hi, lo;
#pragma unroll
  for (int j = 0; j < 8; ++j) {
    float v = src[(size_t)j * HID];
    short h = f2bf(v);
    hi[j] = h;
    lo[j] = f2bf(v - bf2f(h));
  }
  char* dst = wp + ((size_t)((e * 32 + nt) * 16 + kb) << 11) + (lane << 4);
  *(bf16x8*)dst = hi;
  *(bf16x8*)(dst + 1024) = lo;
}

#define MFMA(A, B, C) __builtin_amdgcn_mfma_f32_16x16x32_bf16(A, B, C, 0, 0, 0)

__global__ __launch_bounds__(512, 2) void fused_mlp_kernel(
    const char* __restrict__ xp,
    const char* __restrict__ wp1,
    const char* __restrict__ wp2,
    const float* __restrict__ b1,
    const float* __restrict__ b2,
    const float* __restrict__ w3,
    const float* __restrict__ b3,
    float* __restrict__ out)
{
  __shared__ __align__(16) char lds[IMG_BYTES];
  __shared__ float out_acc[BT];

  const int tid  = threadIdx.x;
  const int lane = tid & 63;
  const int wid  = tid >> 6;       // 8 waves; wave owns cols [wid*64, wid*64+64)

  // XCD-bijective mapping: XCD x works e=2x then e=2x+1 -> 2MB packed W L2-resident
  const int bid   = blockIdx.x;
  const int xcd   = bid & 7;
  const int slot  = bid >> 3;      // 0..255
  const int e     = (xcd << 1) | (slot >> 7);
  const int btile = slot & 127;

  // stage pre-swizzled x image (128 KB) linearly into LDS
  {
    const char* src = xp + (size_t)btile * IMG_BYTES;
#pragma unroll
    for (int it = 0; it < 16; ++it) {
      int off = (it << 13) + (tid << 4);
      *(bf16x8*)(lds + off) = *(const bf16x8*)(src + off);
    }
  }
  if (tid < BT) out_acc[tid] = b3[e];

  // per-lane constants
  const int swzA = (lane & 7) << 4;
  const int h4   = (lane >> 4) << 4;
  int rb[4];
#pragma unroll
  for (int mt = 0; mt < 4; ++mt) rb[mt] = (mt * 16 + (lane & 15)) << 10;

  float bias1[4], bias2[4], w3v[4];
#pragma unroll
  for (int ntl = 0; ntl < 4; ++ntl) {
    int c = wid * 64 + ntl * 16 + (lane & 15);
    bias1[ntl] = b1[e * HID + c];
    bias2[ntl] = b2[e * HID + c];
    w3v[ntl]   = w3[e * HID + c];
  }

  const char* wpe1 = wp1 + (size_t)e * WP_PER_E + (size_t)wid * (4 * 16 * 2048);
  const char* wpe2 = wp2 + (size_t)e * WP_PER_E + (size_t)wid * (4 * 16 * 2048);

  __syncthreads();

  f32x4 acc[4][4];
#pragma unroll
  for (int mt = 0; mt < 4; ++mt)
#pragma unroll
    for (int ntl = 0; ntl < 4; ++ntl)
      acc[mt][ntl] = (f32x4){0.f, 0.f, 0.f, 0.f};

  // ---------------- Layer 1: h1 = relu(x@W1 + b1) ----------------
#pragma unroll 4
  for (int kb = 0; kb < 16; ++kb) {
    bf16x8 Ah[4], Al[4], Bh[4], Bl[4];
    const int ca = ((kb << 6) | h4) ^ swzA;
#pragma unroll
    for (int mt = 0; mt < 4; ++mt) {
      Ah[mt] = *(const bf16x8*)(lds + rb[mt] + ca);
      Al[mt] = *(const bf16x8*)(lds + 65536 + rb[mt] + ca);
    }
#pragma unroll
    for (int ntl = 0; ntl < 4; ++ntl) {
      const char* p = wpe1 + ((ntl * 16 + kb) << 11) + (lane << 4);
      Bh[ntl] = *(const bf16x8*)p;
      Bl[ntl] = *(const bf16x8*)(p + 1024);
    }
#pragma unroll
    for (int mt = 0; mt < 4; ++mt)
#pragma unroll
      for (int ntl = 0; ntl < 4; ++ntl) {
        acc[mt][ntl] = MFMA(Ah[mt], Bh[ntl], acc[mt][ntl]);
        acc[mt][ntl] = MFMA(Ah[mt], Bl[ntl], acc[mt][ntl]);
        acc[mt][ntl] = MFMA(Al[mt], Bh[ntl], acc[mt][ntl]);
      }
  }

  __syncthreads();   // everyone done reading x image

  // bias + relu + hi/lo split, write h1 over the x image (same swizzle)
#pragma unroll
  for (int mt = 0; mt < 4; ++mt)
#pragma unroll
    for (int ntl = 0; ntl < 4; ++ntl) {
      const int C2 = (wid * 64 + ntl * 16 + (lane & 15)) << 1;
#pragma unroll
      for (int q = 0; q < 4; ++q) {
        const int R = mt * 16 + (lane >> 4) * 4 + q;   // C/D row (m89 layout)
        float v = acc[mt][ntl][q] + bias1[ntl];
        v = fmaxf(v, 0.f);
        short hb = f2bf(v);
        short lb = f2bf(v - bf2f(hb));
        const int inrow = C2 ^ ((R & 7) << 4);
        *(short*)(lds + (R << 10) + inrow) = hb;
        *(short*)(lds + 65536 + (R << 10) + inrow) = lb;
      }
    }

  __syncthreads();

#pragma unroll
  for (int mt = 0; mt < 4; ++mt)
#pragma unroll
    for (int ntl = 0; ntl < 4; ++ntl)
      acc[mt][ntl] = (f32x4){0.f, 0.f, 0.f, 0.f};

  // ---------------- Layer 2: h2 = relu(h1@W2 + b2) ----------------
#pragma unroll 4
  for (int kb = 0; kb < 16; ++kb) {
    bf16x8 Ah[4], Al[4], Bh[4], Bl[4];
    const int ca = ((kb << 6) | h4) ^ swzA;
#pragma unroll
    for (int mt = 0; mt < 4; ++mt) {
      Ah[mt] = *(const bf16x8*)(lds + rb[mt] + ca);
      Al[mt] = *(const bf16x8*)(lds + 65536 + rb[mt] + ca);
    }
#pragma unroll
    for (int ntl = 0; ntl < 4; ++ntl) {
      const char* p = wpe2 + ((ntl * 16 + kb) << 11) + (lane << 4);
      Bh[ntl] = *(const bf16x8*)p;
      Bl[ntl] = *(const bf16x8*)(p + 1024);
    }
#pragma unroll
    for (int mt = 0; mt < 4; ++mt)
#pragma unroll
      for (int ntl = 0; ntl < 4; ++ntl) {
        acc[mt][ntl] = MFMA(Ah[mt], Bh[ntl], acc[mt][ntl]);
        acc[mt][ntl] = MFMA(Ah[mt], Bl[ntl], acc[mt][ntl]);
        acc[mt][ntl] = MFMA(Al[mt], Bh[ntl], acc[mt][ntl]);
      }
  }

  // ---------------- Layer 3: out = h2 @ W3 + b3 (in-register) ----------------
#pragma unroll
  for (int mt = 0; mt < 4; ++mt)
#pragma unroll
    for (int q = 0; q < 4; ++q) {
      float p = 0.f;
#pragma unroll
      for (int ntl = 0; ntl < 4; ++ntl)
        p += fmaxf(acc[mt][ntl][q] + bias2[ntl], 0.f) * w3v[ntl];
      // reduce over the 16-lane column group
      p += __shfl_xor(p, 1);
      p += __shfl_xor(p, 2);
      p += __shfl_xor(p, 4);
      p += __shfl_xor(p, 8);
      if ((lane & 15) == 0)
        atomicAdd(&out_acc[mt * 16 + (lane >> 4) * 4 + q], p);
    }

  __syncthreads();
  if (tid < BT)
    out[(size_t)e * BATCH + btile * BT + tid] = out_acc[tid];
}

extern "C" void kernel_launch(void* const* d_in, const int* in_sizes, int n_in,
                              void* d_out, int out_size, void* d_ws, size_t ws_size,
                              hipStream_t stream) {
  (void)in_sizes; (void)n_in; (void)out_size; (void)ws_size;
  const float* x  = (const float*)d_in[0];
  const float* W1 = (const float*)d_in[1];
  const float* b1 = (const float*)d_in[2];
  const float* W2 = (const float*)d_in[3];
  const float* b2 = (const float*)d_in[4];
  const float* W3 = (const float*)d_in[5];
  const float* b3 = (const float*)d_in[6];

  char* xp  = (char*)d_ws;            // 16.78 MB
  char* wp1 = xp + XPACK_BYTES;       // 16.78 MB
  char* wp2 = wp1 + WP_BYTES;         // 16.78 MB  (total ws use ~50.3 MB)

  pack_x_kernel<<<2048, 256, 0, stream>>>(x, xp);
  pack_w_kernel<<<2048, 256, 0, stream>>>(W1, wp1);
  pack_w_kernel<<<2048, 256, 0, stream>>>(W2, wp2);
  fused_mlp_kernel<<<NBLK, 512, 0, stream>>>(xp, wp1, wp2, b1, b2, W3, b3,
                                             (float*)d_out);
}